// Round 18
// baseline (226.580 us; speedup 1.0000x reference)
//
#include <hip/hip_runtime.h>

// B=256, F=16, FO=32, J=22, H=8, IN=256, OUT=512, HID=64, HS=32
// Degenerate-einsum analysis:
//   attn_s = qsum (x) ksum  (outer product of channel sums)
//   x_s    = diag(softmax(attn_s)) * (sum_u v_s')
//   x_t    = sum_f v_t  (softmax sums to 1; q_t/k_t/conv_t/mask_t unused)
// Round 18: register-cliff experiment. Hypothesis: acc[3][4] = 48 AGPRs +
// 64 VGPRs = 112 unified regs/wave -> 4 waves/SIMD -> the 44% occupancy
// plateau of R15-R17. Change: 2 MFMA rounds with acc[3][2] (24 AGPR),
// separate 16KB SoA dump (lA stays live across rounds), m-split gathers,
// char mask. LDS ~53KB -> 3 blocks/CU x 8 waves = 24 waves if regs <= 64.

#define NEGV (-1000000000.0f)

typedef __attribute__((ext_vector_type(8))) short short8;
typedef __attribute__((ext_vector_type(4))) float f32x4;

__device__ inline ushort f2bf(float f) {
  union { float f; unsigned u; } a;
  a.f = f;
  unsigned u = a.u;
  return (ushort)((u + 0x7FFFu + ((u >> 16) & 1u)) >> 16);  // RNE
}

// stage 44 rows x 256 f32 -> bf16 into lA with granule swizzle gp = gl ^ (row&7)
#define PUTG(g, pa, pb)                                                        \
  {                                                                            \
    int row_ = (g) >> 5, gl_ = (g) & 31;                                       \
    int gp_ = gl_ ^ (row_ & 7);                                                \
    short8 u_;                                                                 \
    u_[0] = (short)f2bf(pa[0]); u_[1] = (short)f2bf(pa[1]);                    \
    u_[2] = (short)f2bf(pa[2]); u_[3] = (short)f2bf(pa[3]);                    \
    u_[4] = (short)f2bf(pb[0]); u_[5] = (short)f2bf(pb[1]);                    \
    u_[6] = (short)f2bf(pb[2]); u_[7] = (short)f2bf(pb[3]);                    \
    *reinterpret_cast<short8*>(&lA[row_ * 256 + gp_ * 8]) = u_;                \
  }

#define STAGE44_NT(SRCPTR)                                                     \
  {                                                                            \
    const float* vsrc_ = (SRCPTR);                                             \
    int g0 = tid, g1 = tid + 512, g2 = tid + 1024;                             \
    f32x4 a0 = __builtin_nontemporal_load(                                     \
        reinterpret_cast<const f32x4*>(vsrc_ + g0 * 8));                       \
    f32x4 b0 = __builtin_nontemporal_load(                                     \
        reinterpret_cast<const f32x4*>(vsrc_ + g0 * 8 + 4));                   \
    f32x4 a1 = __builtin_nontemporal_load(                                     \
        reinterpret_cast<const f32x4*>(vsrc_ + g1 * 8));                       \
    f32x4 b1 = __builtin_nontemporal_load(                                     \
        reinterpret_cast<const f32x4*>(vsrc_ + g1 * 8 + 4));                   \
    f32x4 a2 = {0, 0, 0, 0}, b2 = {0, 0, 0, 0};                                \
    if (g2 < 1408) {                                                           \
      a2 = __builtin_nontemporal_load(                                         \
          reinterpret_cast<const f32x4*>(vsrc_ + g2 * 8));                     \
      b2 = __builtin_nontemporal_load(                                         \
          reinterpret_cast<const f32x4*>(vsrc_ + g2 * 8 + 4));                 \
    }                                                                          \
    PUTG(g0, a0, b0);                                                          \
    PUTG(g1, a1, b1);                                                          \
    if (g2 < 1408) PUTG(g2, a2, b2);                                           \
    if (tid < 128) {                                                           \
      int g = 1408 + tid;                                                      \
      int row_ = g >> 5, gp_ = (g & 31) ^ (row_ & 7);                          \
      short8 z = {0, 0, 0, 0, 0, 0, 0, 0};                                     \
      *reinterpret_cast<short8*>(&lA[row_ * 256 + gp_ * 8]) = z;               \
    }                                                                          \
  }

// ---------------- prep_all: wvt (0..255) + qkwf (256..271) + prepb (272) ----
__global__ __launch_bounds__(512) void prep_all_kernel(const float* __restrict__ Wq_w,
                                                       const float* __restrict__ Wq_b,
                                                       const float* __restrict__ Wk_w,
                                                       const float* __restrict__ Wk_b,
                                                       const float* __restrict__ Wv_w,
                                                       ushort* __restrict__ qwf,
                                                       ushort* __restrict__ kwf,
                                                       ushort* __restrict__ wvtf,
                                                       float* __restrict__ sqb,
                                                       float* __restrict__ skb) {
  int bx = blockIdx.x, tid = threadIdx.x;
  if (bx < 256) {
    int idx = bx * 512 + tid;  // 0..131071
    int e = idx & 7;
    int lane = (idx >> 3) & 63;
    int ks = (idx >> 9) & 7;
    int nt = idx >> 12;
    int r0 = lane & 15, kb = lane >> 4;
    int k = ks * 32 + kb * 8 + e;
    int ch = nt * 16 + r0;
    wvtf[idx] = f2bf(Wv_w[k * 512 + ch]);
  } else if (bx < 272) {
    int idx = (bx - 256) * 512 + tid;  // 0..8191
    int which = idx >> 12;
    int r = idx & 4095;
    int e = r & 7;
    int lane = (r >> 3) & 63;
    int ks = r >> 9;
    int m = lane & 15, kb = lane >> 4;
    int k = ks * 32 + kb * 8 + e;
    float s = 0.f;
    if (m < 8) {
      const float* W = which ? Wk_w : Wq_w;
      const float4* p = reinterpret_cast<const float4*>(W + (size_t)k * 512 + m * 64);
      #pragma unroll
      for (int c4 = 0; c4 < 8; ++c4) {
        float4 x = p[c4];
        s += x.x + x.y + x.z + x.w;
      }
    }
    (which ? kwf : qwf)[r] = f2bf(s);
  } else {
    if (tid < 8) {
      float s = 0.f;
      for (int c = 0; c < 32; ++c) s += Wq_b[tid * 64 + c];
      sqb[tid] = s;
    } else if (tid < 16) {
      int mm = tid - 8;
      float s = 0.f;
      for (int c = 0; c < 32; ++c) s += Wk_b[mm * 64 + c];
      skb[mm] = s;
    }
  }
}

// ---------------- mega: everything for head-slice (b,h) in one block --------
__global__ __launch_bounds__(512, 2) void mega_kernel(const float* __restrict__ q,
                                                      const float* __restrict__ k,
                                                      const float* __restrict__ v,
                                                      const ushort* __restrict__ qwf,
                                                      const ushort* __restrict__ kwf,
                                                      const ushort* __restrict__ wvtf,
                                                      const float* __restrict__ sqb,
                                                      const float* __restrict__ skb,
                                                      const float* __restrict__ Wv_b,
                                                      const float* __restrict__ csw,
                                                      const float* __restrict__ csb,
                                                      const int* __restrict__ mask_s,
                                                      float* __restrict__ out) {
  int bh = blockIdx.x;  // b*8 + h
  int b = bh >> 3, h = bh & 7;
  __shared__ ushort lA[48 * 256];  // 24.6KB, live through both MFMA rounds
  __shared__ float dmp[4096];      // 16KB SoA dump; overlay kss/vss/dg later
  __shared__ float qs[32][23];
  __shared__ float kraw[16][23];
  __shared__ float vsg[16][33];
  __shared__ float vtl[22][33];
  __shared__ float lcsw[32][17];
  __shared__ char msk[484];
  float* kssp = dmp;               // [32][23] -> 736
  float* vssp = dmp + 736;         // [32][33] -> 1056
  float* dgp = dmp + 1792;         // [32][23] -> 736  (2528 <= 4096)
  int tid = threadIdx.x, lane = tid & 63, w = tid >> 6;
  int r0 = lane & 15, kb = lane >> 4;

  // ---- 1. v stage (nt loads in flight first) ----
  STAGE44_NT(v + (size_t)bh * 11264);

  // ---- 2. constants ----
  if (tid < 484) msk[tid] = (char)mask_s[tid];
  {
    int t = tid >> 4, f = tid & 15;
    lcsw[t][f] = csw[t * 16 + f];
  }
  if (tid < 32) lcsw[tid][16] = csb[tid];

  // ---- 3. q/k direct tiles (no barrier; unique LDS scatter) ----
  const float* qbase = q + (size_t)(b * 704 + 4 * h * 22) * 256;
  const float* kbase = k + (size_t)(b * 352 + 2 * h * 22) * 256;
  for (int pass = 0; pass < 2; ++pass) {
    int u = pass == 0 ? w : 8;
    if (pass == 1 && w != 0) break;
    bool isK = u >= 6;
    int ut = isK ? u - 6 : u;
    int limit = isK ? 44 : 88;
    int rr = ut * 16 + r0;
    if (rr >= limit) rr = 0;  // clamp (results guarded on store)
    const float* src = (isK ? kbase : qbase) + (size_t)rr * 256;
    const ushort* wf = isK ? kwf : qwf;
    f32x4 acc = {0.f, 0.f, 0.f, 0.f};
    #pragma unroll
    for (int ks = 0; ks < 8; ++ks) {
      f32x4 xa = __builtin_nontemporal_load(
          reinterpret_cast<const f32x4*>(src + ks * 32 + kb * 8));
      f32x4 xb = __builtin_nontemporal_load(
          reinterpret_cast<const f32x4*>(src + ks * 32 + kb * 8 + 4));
      short8 a;
      a[0] = (short)f2bf(xa[0]); a[1] = (short)f2bf(xa[1]);
      a[2] = (short)f2bf(xa[2]); a[3] = (short)f2bf(xa[3]);
      a[4] = (short)f2bf(xb[0]); a[5] = (short)f2bf(xb[1]);
      a[6] = (short)f2bf(xb[2]); a[7] = (short)f2bf(xb[3]);
      short8 bf = *reinterpret_cast<const short8*>(wf + (ks * 64 + lane) * 8);
      acc = __builtin_amdgcn_mfma_f32_16x16x32_bf16(a, bf, acc, 0, 0, 0);
    }
    if (r0 < 8) {  // D: col = lane&15 = m, row = kb*4+reg (m89-verified)
      int m = r0;
      float bias = isK ? skb[m] : sqb[m];
      #pragma unroll
      for (int reg = 0; reg < 4; ++reg) {
        int R = ut * 16 + kb * 4 + reg;
        if (R < limit) {
          if (!isK) {
            int fo2l = R / 22, j2 = R % 22;
            int lf = fo2l * 11264 + j2 * 512 + m * 64;
            int t = lf / 1408;
            int s = (lf % 1408) >> 6;
            qs[t][s] = acc[reg] + bias;
          } else {
            int f2l = R / 22, j2 = R % 22;
            int lf = f2l * 11264 + j2 * 512 + m * 64;
            int floc = lf / 1408;
            int jj = (lf % 1408) >> 6;
            kraw[floc][jj] = acc[reg] + bias;
          }
        }
      }
    }
  }
  __syncthreads();  // lA staged + qs/kraw complete

  // ---- 4. v MFMA, 2 rounds of 2 n-tiles (acc[3][2] = 24 regs) ----
  int nt0 = w * 4;
  #pragma unroll
  for (int r = 0; r < 2; ++r) {
    f32x4 acc[3][2];
    #pragma unroll
    for (int m = 0; m < 3; ++m)
      #pragma unroll
      for (int nl = 0; nl < 2; ++nl) acc[m][nl] = (f32x4){0.f, 0.f, 0.f, 0.f};

    #pragma unroll
    for (int ks = 0; ks < 8; ++ks) {
      int go = ((ks * 4 + kb) ^ (r0 & 7)) * 8;
      short8 a0 = *reinterpret_cast<const short8*>(&lA[(r0) * 256 + go]);
      short8 a1 = *reinterpret_cast<const short8*>(&lA[(16 + r0) * 256 + go]);
      short8 a2 = *reinterpret_cast<const short8*>(&lA[(32 + r0) * 256 + go]);
      #pragma unroll
      for (int nl = 0; nl < 2; ++nl) {
        short8 bf = *reinterpret_cast<const short8*>(
            wvtf + ((size_t)((nt0 + r * 2 + nl) * 8 + ks) * 64 + lane) * 8);
        acc[0][nl] = __builtin_amdgcn_mfma_f32_16x16x32_bf16(bf, a0, acc[0][nl], 0, 0, 0);
        acc[1][nl] = __builtin_amdgcn_mfma_f32_16x16x32_bf16(bf, a1, acc[1][nl], 0, 0, 0);
        acc[2][nl] = __builtin_amdgcn_mfma_f32_16x16x32_bf16(bf, a2, acc[2][nl], 0, 0, 0);
      }
    }

    // ---- 5. dump/gather: per n, m-split {0,1} then {2}; SoA dmp[e*512+src]
    #pragma unroll
    for (int nl = 0; nl < 2; ++nl) {
      int n = r * 2 + nl;
      float4 bq = *reinterpret_cast<const float4*>(Wv_b + w * 64 + n * 16 + kb * 4);
      #pragma unroll
      for (int msub = 0; msub < 2; ++msub) {
        __syncthreads();  // prior gather done reading dmp
        if (msub == 0) {
          #pragma unroll
          for (int m = 0; m < 2; ++m) {
            dmp[(m * 4 + 0) * 512 + tid] = acc[m][nl][0] + bq.x;
            dmp[(m * 4 + 1) * 512 + tid] = acc[m][nl][1] + bq.y;
            dmp[(m * 4 + 2) * 512 + tid] = acc[m][nl][2] + bq.z;
            dmp[(m * 4 + 3) * 512 + tid] = acc[m][nl][3] + bq.w;
          }
        } else {
          dmp[0 * 512 + tid] = acc[2][nl][0] + bq.x;
          dmp[1 * 512 + tid] = acc[2][nl][1] + bq.y;
          dmp[2 * 512 + tid] = acc[2][nl][2] + bq.z;
          dmp[3 * 512 + tid] = acc[2][nl][3] + bq.w;
        }
        __syncthreads();
        if (n < 2) {
          if (tid < 256) {
            int f = tid >> 4, rest = tid & 15;
            int kb2 = rest >> 2, reg = rest & 3;
            float s = 0.f;
            #pragma unroll
            for (int u = 0; u < 22; ++u) {
              int fj = f * 22 + u;
              int f2 = (fj >= 176) ? 1 : 0;
              int rem = fj - f2 * 176;
              int j = rem >> 3, ww = rem & 7;
              int vrow = f2 * 22 + j;
              int m = vrow >> 4, rr2 = vrow & 15;
              int src = ww * 64 + kb2 * 16 + rr2;
              if (msub == 0) {
                if (m < 2) s += dmp[(m * 4 + reg) * 512 + src];
              } else {
                if (m == 2) s += dmp[reg * 512 + src];
              }
            }
            int d = n * 16 + kb2 * 4 + reg;
            if (msub == 0) vsg[f][d] = s;
            else vsg[f][d] += s;
          }
        } else {
          if (tid < 352) {
            int jj = tid >> 4, rest = tid & 15;
            int kb2 = rest >> 2, reg = rest & 3;
            float s = 0.f;
            #pragma unroll
            for (int f = 0; f < 16; ++f) {
              int fj = f * 22 + jj;
              int f2 = (fj >= 176) ? 1 : 0;
              int rem = fj - f2 * 176;
              int j = rem >> 3, ww = rem & 7;
              int vrow = f2 * 22 + j;
              int m = vrow >> 4, rr2 = vrow & 15;
              int src = ww * 64 + kb2 * 16 + rr2;
              if (msub == 0) {
                if (m < 2) s += dmp[(m * 4 + reg) * 512 + src];
              } else {
                if (m == 2) s += dmp[reg * 512 + src];
              }
            }
            int g = (n - 2) * 16 + kb2 * 4 + reg;
            if (msub == 0) vtl[jj][g] = s;
            else vtl[jj][g] += s;
          }
        }
      }
    }
  }
  __syncthreads();  // all gathers done; dmp free for overlay; vtl complete

  // ---- 6a. EARLY vt-half output write: overlaps convs/softmax ----
  float* ob = out + (size_t)b * 32 * 22 * 512 + h * 64;
  for (int i = tid; i < 5632; i += 512) {   // 32 t x 22 s x 8 float4
    int ts = i >> 3, w4 = i & 7;
    int t = ts / 22, s = ts % 22;
    int d0 = 32 + w4 * 4;
    const float* tp = &vtl[s][d0 - 32];
    f32x4 val = {tp[0], tp[1], tp[2], tp[3]};
    *reinterpret_cast<f32x4*>(ob + (size_t)(t * 22 + s) * 512 + d0) = val;
  }

  // ---- 6b. convs: kss (704) and vss (1024) — into dmp overlay ----
  for (int o = tid; o < 704; o += 512) {
    int t = o / 22, j = o % 22;
    float a = 32.0f * lcsw[t][16];
    #pragma unroll
    for (int f = 0; f < 16; ++f) a += lcsw[t][f] * kraw[f][j];
    kssp[t * 23 + j] = a;
  }
  {
    int t = tid >> 4, d2 = (tid & 15) * 2;
    float a0 = 22.0f * lcsw[t][16], a1 = a0;
    #pragma unroll
    for (int f = 0; f < 16; ++f) {
      float cw = lcsw[t][f];
      a0 += cw * vsg[f][d2];
      a1 += cw * vsg[f][d2 + 1];
    }
    vssp[t * 33 + d2] = a0;
    vssp[t * 33 + d2 + 1] = a1;
  }
  __syncthreads();

  // ---- 7. diag softmax (704) ----
  for (int p = tid; p < 704; p += 512) {
    int t = p / 22, s = p % 22;
    float qv = qs[t][s];
    float mx = -3.0e38f;
    #pragma unroll
    for (int u = 0; u < 22; ++u) {
      float av = msk[s * 22 + u] ? qv * kssp[t * 23 + u] : NEGV;
      mx = fmaxf(mx, av);
    }
    float den = 0.f;
    #pragma unroll
    for (int u = 0; u < 22; ++u) {
      float av = msk[s * 22 + u] ? qv * kssp[t * 23 + u] : NEGV;
      den += expf(av - mx);
    }
    float as = msk[s * 22 + s] ? qv * kssp[t * 23 + s] : NEGV;
    dgp[t * 23 + s] = expf(as - mx) / den;
  }
  __syncthreads();

  // ---- 8. vs-half output write (plain stores) ----
  for (int i = tid; i < 5632; i += 512) {   // 32 t x 22 s x 8 float4
    int ts = i >> 3, w4 = i & 7;
    int t = ts / 22, s = ts % 22;
    int d0 = w4 * 4;
    float g = dgp[t * 23 + s];
    const float* vp = &vssp[t * 33 + d0];
    f32x4 val = {g * vp[0], g * vp[1], g * vp[2], g * vp[3]};
    *reinterpret_cast<f32x4*>(ob + (size_t)(t * 22 + s) * 512 + d0) = val;
  }
}

extern "C" void kernel_launch(void* const* d_in, const int* in_sizes, int n_in,
                              void* d_out, int out_size, void* d_ws, size_t ws_size,
                              hipStream_t stream) {
  const float* q = (const float*)d_in[0];
  const float* k = (const float*)d_in[1];
  const float* v = (const float*)d_in[2];
  const int* mask_s = (const int*)d_in[3];
  const float* Wq_w = (const float*)d_in[5];
  const float* Wq_b = (const float*)d_in[6];
  const float* Wk_w = (const float*)d_in[7];
  const float* Wk_b = (const float*)d_in[8];
  const float* Wv_w = (const float*)d_in[9];
  const float* Wv_b = (const float*)d_in[10];
  const float* csw = (const float*)d_in[11];
  const float* csb = (const float*)d_in[12];
  float* out = (float*)d_out;

  float* ws = (float*)d_ws;
  float* sqb = ws;                            // 8
  float* skb = ws + 8;                        // 8 -> 16
  ushort* wvtf = (ushort*)(ws + 16);          // 131072 us -> ends f-idx 65552
  ushort* qwf = (ushort*)(ws + 65552);        // 4096 us -> 67600
  ushort* kwf = (ushort*)(ws + 67600);        // 4096 us -> 69648

  hipLaunchKernelGGL(prep_all_kernel, dim3(273), dim3(512), 0, stream,
                     Wq_w, Wq_b, Wk_w, Wk_b, Wv_w, qwf, kwf, wvtf, sqb, skb);
  hipLaunchKernelGGL(mega_kernel, dim3(2048), dim3(512), 0, stream,
                     q, k, v, qwf, kwf, wvtf, sqb, skb, Wv_b, csw, csb, mask_s, out);
}

// Round 19
// 187.573 us; speedup vs baseline: 1.2080x; 1.2080x over previous
//
#include <hip/hip_runtime.h>

// B=256, F=16, FO=32, J=22, H=8, IN=256, OUT=512, HID=64, HS=32
// Degenerate-einsum analysis:
//   attn_s = qsum (x) ksum  (outer product of channel sums)
//   x_s    = diag(softmax(attn_s)) * (sum_u v_s')
//   x_t    = sum_f v_t  (softmax sums to 1; q_t/k_t/conv_t/mask_t unused)
// Round 19: REVERT to R17 (187.9us best). R18 refuted the register-cliff
// theory (VGPR 64->44, occupancy unchanged 46%, dur +21% from SoA-dump
// 4-way bank conflicts (512 = 0 mod 32 banks) + doubled barriers).
// Occupancy plateau = intra-block barrier-phase structure, not resources.

#define NEGV (-1000000000.0f)

typedef __attribute__((ext_vector_type(8))) short short8;
typedef __attribute__((ext_vector_type(4))) float f32x4;

__device__ inline ushort f2bf(float f) {
  union { float f; unsigned u; } a;
  a.f = f;
  unsigned u = a.u;
  return (ushort)((u + 0x7FFFu + ((u >> 16) & 1u)) >> 16);  // RNE
}

// stage 44 rows x 256 f32 -> bf16 into lA with granule swizzle gp = gl ^ (row&7)
#define PUTG(g, pa, pb)                                                        \
  {                                                                            \
    int row_ = (g) >> 5, gl_ = (g) & 31;                                       \
    int gp_ = gl_ ^ (row_ & 7);                                                \
    short8 u_;                                                                 \
    u_[0] = (short)f2bf(pa[0]); u_[1] = (short)f2bf(pa[1]);                    \
    u_[2] = (short)f2bf(pa[2]); u_[3] = (short)f2bf(pa[3]);                    \
    u_[4] = (short)f2bf(pb[0]); u_[5] = (short)f2bf(pb[1]);                    \
    u_[6] = (short)f2bf(pb[2]); u_[7] = (short)f2bf(pb[3]);                    \
    *reinterpret_cast<short8*>(&lA[row_ * 256 + gp_ * 8]) = u_;                \
  }

#define STAGE44_NT(SRCPTR)                                                     \
  {                                                                            \
    const float* vsrc_ = (SRCPTR);                                             \
    int g0 = tid, g1 = tid + 512, g2 = tid + 1024;                             \
    f32x4 a0 = __builtin_nontemporal_load(                                     \
        reinterpret_cast<const f32x4*>(vsrc_ + g0 * 8));                       \
    f32x4 b0 = __builtin_nontemporal_load(                                     \
        reinterpret_cast<const f32x4*>(vsrc_ + g0 * 8 + 4));                   \
    f32x4 a1 = __builtin_nontemporal_load(                                     \
        reinterpret_cast<const f32x4*>(vsrc_ + g1 * 8));                       \
    f32x4 b1 = __builtin_nontemporal_load(                                     \
        reinterpret_cast<const f32x4*>(vsrc_ + g1 * 8 + 4));                   \
    f32x4 a2 = {0, 0, 0, 0}, b2 = {0, 0, 0, 0};                                \
    if (g2 < 1408) {                                                           \
      a2 = __builtin_nontemporal_load(                                         \
          reinterpret_cast<const f32x4*>(vsrc_ + g2 * 8));                     \
      b2 = __builtin_nontemporal_load(                                         \
          reinterpret_cast<const f32x4*>(vsrc_ + g2 * 8 + 4));                 \
    }                                                                          \
    PUTG(g0, a0, b0);                                                          \
    PUTG(g1, a1, b1);                                                          \
    if (g2 < 1408) PUTG(g2, a2, b2);                                           \
    if (tid < 128) {                                                           \
      int g = 1408 + tid;                                                      \
      int row_ = g >> 5, gp_ = (g & 31) ^ (row_ & 7);                          \
      short8 z = {0, 0, 0, 0, 0, 0, 0, 0};                                     \
      *reinterpret_cast<short8*>(&lA[row_ * 256 + gp_ * 8]) = z;               \
    }                                                                          \
  }

// ---------------- prep_all: wvt (0..255) + qkwf (256..271) + prepb (272) ----
__global__ __launch_bounds__(512) void prep_all_kernel(const float* __restrict__ Wq_w,
                                                       const float* __restrict__ Wq_b,
                                                       const float* __restrict__ Wk_w,
                                                       const float* __restrict__ Wk_b,
                                                       const float* __restrict__ Wv_w,
                                                       ushort* __restrict__ qwf,
                                                       ushort* __restrict__ kwf,
                                                       ushort* __restrict__ wvtf,
                                                       float* __restrict__ sqb,
                                                       float* __restrict__ skb) {
  int bx = blockIdx.x, tid = threadIdx.x;
  if (bx < 256) {
    int idx = bx * 512 + tid;  // 0..131071
    int e = idx & 7;
    int lane = (idx >> 3) & 63;
    int ks = (idx >> 9) & 7;
    int nt = idx >> 12;
    int r0 = lane & 15, kb = lane >> 4;
    int k = ks * 32 + kb * 8 + e;
    int ch = nt * 16 + r0;
    wvtf[idx] = f2bf(Wv_w[k * 512 + ch]);
  } else if (bx < 272) {
    int idx = (bx - 256) * 512 + tid;  // 0..8191
    int which = idx >> 12;
    int r = idx & 4095;
    int e = r & 7;
    int lane = (r >> 3) & 63;
    int ks = r >> 9;
    int m = lane & 15, kb = lane >> 4;
    int k = ks * 32 + kb * 8 + e;
    float s = 0.f;
    if (m < 8) {
      const float* W = which ? Wk_w : Wq_w;
      const float4* p = reinterpret_cast<const float4*>(W + (size_t)k * 512 + m * 64);
      #pragma unroll
      for (int c4 = 0; c4 < 8; ++c4) {
        float4 x = p[c4];
        s += x.x + x.y + x.z + x.w;
      }
    }
    (which ? kwf : qwf)[r] = f2bf(s);
  } else {
    if (tid < 8) {
      float s = 0.f;
      for (int c = 0; c < 32; ++c) s += Wq_b[tid * 64 + c];
      sqb[tid] = s;
    } else if (tid < 16) {
      int mm = tid - 8;
      float s = 0.f;
      for (int c = 0; c < 32; ++c) s += Wk_b[mm * 64 + c];
      skb[mm] = s;
    }
  }
}

// ---------------- mega: everything for head-slice (b,h) in one block --------
__global__ __launch_bounds__(512, 2) void mega_kernel(const float* __restrict__ q,
                                                      const float* __restrict__ k,
                                                      const float* __restrict__ v,
                                                      const ushort* __restrict__ qwf,
                                                      const ushort* __restrict__ kwf,
                                                      const ushort* __restrict__ wvtf,
                                                      const float* __restrict__ sqb,
                                                      const float* __restrict__ skb,
                                                      const float* __restrict__ Wv_b,
                                                      const float* __restrict__ csw,
                                                      const float* __restrict__ csb,
                                                      const int* __restrict__ mask_s,
                                                      float* __restrict__ out) {
  int bh = blockIdx.x;  // b*8 + h
  int b = bh >> 3, h = bh & 7;
  __shared__ float sbuf[6656];     // lA (24.6KB) / dump (26.6KB) / kss+vss+dg
  __shared__ float qs[32][23];     // qsum[t][s]
  __shared__ float kraw[16][23];   // ksumraw[floc][j]
  __shared__ float vsg[16][33];    // vs_inner[f][d]
  __shared__ float vtl[22][33];    // vtsum[j][g]
  __shared__ float lcsw[32][17];   // csw[t][f], csb in [16]
  __shared__ int msk[484];
  ushort* lA = reinterpret_cast<ushort*>(sbuf);
  float* dump = sbuf;
  // overlay (live only after gather phases; sbuf dead then):
  float* kssp = sbuf;              // [32][23] -> 736
  float* vssp = sbuf + 736;        // [32][33] -> 1056
  float* dgp = sbuf + 1792;        // [32][23] -> 736   (total 2528 <= 6656)
  int tid = threadIdx.x, lane = tid & 63, w = tid >> 6;
  int r0 = lane & 15, kb = lane >> 4;

  // ---- 1. v stage (nt loads in flight first) ----
  STAGE44_NT(v + (size_t)bh * 11264);

  // ---- 2. constants ----
  if (tid < 484) msk[tid] = mask_s[tid];
  {
    int t = tid >> 4, f = tid & 15;
    lcsw[t][f] = csw[t * 16 + f];
  }
  if (tid < 32) lcsw[tid][16] = csb[tid];

  // ---- 3. q/k direct tiles (no barrier; unique LDS scatter) ----
  const float* qbase = q + (size_t)(b * 704 + 4 * h * 22) * 256;
  const float* kbase = k + (size_t)(b * 352 + 2 * h * 22) * 256;
  for (int pass = 0; pass < 2; ++pass) {
    int u = pass == 0 ? w : 8;
    if (pass == 1 && w != 0) break;
    bool isK = u >= 6;
    int ut = isK ? u - 6 : u;
    int limit = isK ? 44 : 88;
    int rr = ut * 16 + r0;
    if (rr >= limit) rr = 0;  // clamp (results guarded on store)
    const float* src = (isK ? kbase : qbase) + (size_t)rr * 256;
    const ushort* wf = isK ? kwf : qwf;
    f32x4 acc = {0.f, 0.f, 0.f, 0.f};
    #pragma unroll
    for (int ks = 0; ks < 8; ++ks) {
      f32x4 xa = __builtin_nontemporal_load(
          reinterpret_cast<const f32x4*>(src + ks * 32 + kb * 8));
      f32x4 xb = __builtin_nontemporal_load(
          reinterpret_cast<const f32x4*>(src + ks * 32 + kb * 8 + 4));
      short8 a;
      a[0] = (short)f2bf(xa[0]); a[1] = (short)f2bf(xa[1]);
      a[2] = (short)f2bf(xa[2]); a[3] = (short)f2bf(xa[3]);
      a[4] = (short)f2bf(xb[0]); a[5] = (short)f2bf(xb[1]);
      a[6] = (short)f2bf(xb[2]); a[7] = (short)f2bf(xb[3]);
      short8 bf = *reinterpret_cast<const short8*>(wf + (ks * 64 + lane) * 8);
      acc = __builtin_amdgcn_mfma_f32_16x16x32_bf16(a, bf, acc, 0, 0, 0);
    }
    if (r0 < 8) {  // D: col = lane&15 = m, row = kb*4+reg (m89-verified)
      int m = r0;
      float bias = isK ? skb[m] : sqb[m];
      #pragma unroll
      for (int reg = 0; reg < 4; ++reg) {
        int R = ut * 16 + kb * 4 + reg;  // local row
        if (R < limit) {
          if (!isK) {
            int fo2l = R / 22, j2 = R % 22;
            int lf = fo2l * 11264 + j2 * 512 + m * 64;
            int t = lf / 1408;
            int s = (lf % 1408) >> 6;
            qs[t][s] = acc[reg] + bias;
          } else {
            int f2l = R / 22, j2 = R % 22;
            int lf = f2l * 11264 + j2 * 512 + m * 64;
            int floc = lf / 1408;
            int jj = (lf % 1408) >> 6;
            kraw[floc][jj] = acc[reg] + bias;
          }
        }
      }
    }
  }
  __syncthreads();  // lA staged + qs/kraw complete

  // ---- 4. v MFMA (R10-verified body) ----
  int nt0 = w * 4;
  f32x4 acc[3][4];
  #pragma unroll
  for (int m = 0; m < 3; ++m)
    #pragma unroll
    for (int n = 0; n < 4; ++n) acc[m][n] = (f32x4){0.f, 0.f, 0.f, 0.f};

  #pragma unroll
  for (int ks = 0; ks < 8; ++ks) {
    int go = ((ks * 4 + kb) ^ (r0 & 7)) * 8;
    short8 a0 = *reinterpret_cast<const short8*>(&lA[(r0) * 256 + go]);
    short8 a1 = *reinterpret_cast<const short8*>(&lA[(16 + r0) * 256 + go]);
    short8 a2 = *reinterpret_cast<const short8*>(&lA[(32 + r0) * 256 + go]);
    #pragma unroll
    for (int n = 0; n < 4; ++n) {
      short8 bf = *reinterpret_cast<const short8*>(
          wvtf + ((size_t)((nt0 + n) * 8 + ks) * 64 + lane) * 8);
      acc[0][n] = __builtin_amdgcn_mfma_f32_16x16x32_bf16(bf, a0, acc[0][n], 0, 0, 0);
      acc[1][n] = __builtin_amdgcn_mfma_f32_16x16x32_bf16(bf, a1, acc[1][n], 0, 0, 0);
      acc[2][n] = __builtin_amdgcn_mfma_f32_16x16x32_bf16(bf, a2, acc[2][n], 0, 0, 0);
    }
  }
  __syncthreads();  // lA reads done; sbuf becomes dump

  // ---- 5. dump/gather 4 phases -> vsg / vtl (LDS) ----
  #pragma unroll
  for (int n = 0; n < 4; ++n) {
    float4 bq = *reinterpret_cast<const float4*>(Wv_b + w * 64 + n * 16 + kb * 4);
    int dbase = tid * 13;
    #pragma unroll
    for (int m = 0; m < 3; ++m) {
      dump[dbase + m * 4 + 0] = acc[m][n][0] + bq.x;
      dump[dbase + m * 4 + 1] = acc[m][n][1] + bq.y;
      dump[dbase + m * 4 + 2] = acc[m][n][2] + bq.z;
      dump[dbase + m * 4 + 3] = acc[m][n][3] + bq.w;
    }
    __syncthreads();
    if (n < 2) {
      if (tid < 256) {
        int f = tid >> 4, rest = tid & 15;
        int kb2 = rest >> 2, reg = rest & 3;
        float s = 0.f;
        #pragma unroll
        for (int u = 0; u < 22; ++u) {
          int fj = f * 22 + u;
          int f2 = (fj >= 176) ? 1 : 0;
          int rem = fj - f2 * 176;
          int j = rem >> 3, ww = rem & 7;
          int vrow = f2 * 22 + j;
          int m = vrow >> 4, rr2 = vrow & 15;
          s += dump[(ww * 64 + kb2 * 16 + rr2) * 13 + m * 4 + reg];
        }
        vsg[f][n * 16 + kb2 * 4 + reg] = s;
      }
    } else {
      if (tid < 352) {
        int jj = tid >> 4, rest = tid & 15;
        int kb2 = rest >> 2, reg = rest & 3;
        float s = 0.f;
        #pragma unroll
        for (int f = 0; f < 16; ++f) {
          int fj = f * 22 + jj;
          int f2 = (fj >= 176) ? 1 : 0;
          int rem = fj - f2 * 176;
          int j = rem >> 3, ww = rem & 7;
          int vrow = f2 * 22 + j;
          int m = vrow >> 4, rr2 = vrow & 15;
          s += dump[(ww * 64 + kb2 * 16 + rr2) * 13 + m * 4 + reg];
        }
        vtl[jj][(n - 2) * 16 + kb2 * 4 + reg] = s;
      }
    }
    __syncthreads();
  }

  // ---- 6a. EARLY vt-half output write (t-independent): overlaps convs/softmax
  float* ob = out + (size_t)b * 32 * 22 * 512 + h * 64;
  for (int i = tid; i < 5632; i += 512) {   // 32 t x 22 s x 8 float4
    int ts = i >> 3, w4 = i & 7;
    int t = ts / 22, s = ts % 22;
    int d0 = 32 + w4 * 4;
    const float* tp = &vtl[s][d0 - 32];
    f32x4 val = {tp[0], tp[1], tp[2], tp[3]};
    *reinterpret_cast<f32x4*>(ob + (size_t)(t * 22 + s) * 512 + d0) = val;
  }

  // ---- 6b. convs: kss (704) and vss (1024) — into sbuf overlay ----
  for (int o = tid; o < 704; o += 512) {
    int t = o / 22, j = o % 22;
    float a = 32.0f * lcsw[t][16];
    #pragma unroll
    for (int f = 0; f < 16; ++f) a += lcsw[t][f] * kraw[f][j];
    kssp[t * 23 + j] = a;
  }
  {
    int t = tid >> 4, d2 = (tid & 15) * 2;
    float a0 = 22.0f * lcsw[t][16], a1 = a0;
    #pragma unroll
    for (int f = 0; f < 16; ++f) {
      float cw = lcsw[t][f];
      a0 += cw * vsg[f][d2];
      a1 += cw * vsg[f][d2 + 1];
    }
    vssp[t * 33 + d2] = a0;
    vssp[t * 33 + d2 + 1] = a1;
  }
  __syncthreads();

  // ---- 7. diag softmax (704) ----
  for (int p = tid; p < 704; p += 512) {
    int t = p / 22, s = p % 22;
    float qv = qs[t][s];
    float mx = -3.0e38f;
    #pragma unroll
    for (int u = 0; u < 22; ++u) {
      float av = msk[s * 22 + u] ? qv * kssp[t * 23 + u] : NEGV;
      mx = fmaxf(mx, av);
    }
    float den = 0.f;
    #pragma unroll
    for (int u = 0; u < 22; ++u) {
      float av = msk[s * 22 + u] ? qv * kssp[t * 23 + u] : NEGV;
      den += expf(av - mx);
    }
    float as = msk[s * 22 + s] ? qv * kssp[t * 23 + s] : NEGV;
    dgp[t * 23 + s] = expf(as - mx) / den;
  }
  __syncthreads();

  // ---- 8. vs-half output write (plain stores) ----
  for (int i = tid; i < 5632; i += 512) {   // 32 t x 22 s x 8 float4
    int ts = i >> 3, w4 = i & 7;
    int t = ts / 22, s = ts % 22;
    int d0 = w4 * 4;
    float g = dgp[t * 23 + s];
    const float* vp = &vssp[t * 33 + d0];
    f32x4 val = {g * vp[0], g * vp[1], g * vp[2], g * vp[3]};
    *reinterpret_cast<f32x4*>(ob + (size_t)(t * 22 + s) * 512 + d0) = val;
  }
}

extern "C" void kernel_launch(void* const* d_in, const int* in_sizes, int n_in,
                              void* d_out, int out_size, void* d_ws, size_t ws_size,
                              hipStream_t stream) {
  const float* q = (const float*)d_in[0];
  const float* k = (const float*)d_in[1];
  const float* v = (const float*)d_in[2];
  const int* mask_s = (const int*)d_in[3];
  const float* Wq_w = (const float*)d_in[5];
  const float* Wq_b = (const float*)d_in[6];
  const float* Wk_w = (const float*)d_in[7];
  const float* Wk_b = (const float*)d_in[8];
  const float* Wv_w = (const float*)d_in[9];
  const float* Wv_b = (const float*)d_in[10];
  const float* csw = (const float*)d_in[11];
  const float* csb = (const float*)d_in[12];
  float* out = (float*)d_out;

  float* ws = (float*)d_ws;
  float* sqb = ws;                            // 8
  float* skb = ws + 8;                        // 8 -> 16
  ushort* wvtf = (ushort*)(ws + 16);          // 131072 us -> ends f-idx 65552
  ushort* qwf = (ushort*)(ws + 65552);        // 4096 us -> 67600
  ushort* kwf = (ushort*)(ws + 67600);        // 4096 us -> 69648

  hipLaunchKernelGGL(prep_all_kernel, dim3(273), dim3(512), 0, stream,
                     Wq_w, Wq_b, Wk_w, Wk_b, Wv_w, qwf, kwf, wvtf, sqb, skb);
  hipLaunchKernelGGL(mega_kernel, dim3(2048), dim3(512), 0, stream,
                     q, k, v, qwf, kwf, wvtf, sqb, skb, Wv_b, csw, csb, mask_s, out);
}